// Round 9
// baseline (11942.155 us; speedup 1.0000x reference)
//
#include <hip/hip_runtime.h>
#include <stdint.h>

// Farthest point sampling: b=16, n=65536, npoints=2048. Full-f64 decision
// pipeline (R5: harness ref is float64 ground-truth recompute; R5-R8 absmax 0).
//
// R9: hierarchical rendezvous. R8 taught: slot lines must be SINGLE-WRITER
// (false sharing doubled WRITE_SIZE and regressed); R6->R7 delta taught:
// an agent-scope hop costs ~1500-2000 cy, so cut participants, not bytes.
//  - 8 blocks x 512 threads per batch (16 pts/thread unchanged). The 8
//    waves pre-reduce via LDS (one __syncthreads, intra-CU ~100 cy) ->
//    ONE publisher (tid 0) per block -> 8 slots per batch.
//  - Slot = one 64-B line (single writer), 4 self-tagged u64 words:
//      w0=[bd_hi32|tag|idx] w1=[bd_lo32|tag|x_hi16]
//      w2=[y|tag|x_lo16]    w3=[z|tag|idx]
//  - Poll: lane i reads slot (i&7) -> 8 lines per retry (vs 64 in R7).
//    3-stage butterfly within each 8-lane group; winner slot derived from
//    idx (blk = ci>>13); coords shuffled from that slot's lane.
//  - g = bid&15 with 128 blocks: a batch's 8 blocks land on one XCD under
//    round-robin dispatch (16 = 0 mod 8) — locality heuristic only.
// Protocol invariants unchanged (parity double-buffer, unique 16-bit tags,
// poison 0xAAAA unmatchable, skew <= 1 iteration via the rendezvous chain).

#define NBATCH   16
#define NPTS     65536
#define NPOINTS  2048
#define KBLK     8                   // blocks per batch
#define THREADS  512
#define WAVES    8                   // waves per block
#define PPB      8192                // points per block (KBLK*THREADS*PPT=N)
#define PPT      16                  // points per thread
#define SLOT_U64 8                   // one 64-B line per slot, single writer
#define REGION_U64 (KBLK * SLOT_U64) // 512 B per (parity,batch)

__global__ __launch_bounds__(THREADS, 1)
void fps_kernel(const float* __restrict__ pts, int* __restrict__ out,
                unsigned long long* __restrict__ slots)
{
    const int bid  = blockIdx.x;
    const int g    = bid & 15;       // batch (XCD co-location swizzle)
    const int blk  = bid >> 4;       // block within batch, 0..7
    const int tid  = threadIdx.x;
    const int lane = tid & 63;
    const int wave = tid >> 6;       // 0..7

    const float* __restrict__ P = pts + (size_t)g * (NPTS * 3);

    __shared__ double s_bd[WAVES];
    __shared__ int    s_bi[WAVES];
    __shared__ float  s_x[WAVES], s_y[WAVES], s_z[WAVES];

    // Register-resident coords (f32; exact when widened to f64) + f64 dist.
    float  x[PPT], y[PPT], z[PPT];
    double dist[PPT];
    const int base = blk * PPB;
#pragma unroll
    for (int j = 0; j < PPT; ++j) {
        const int idx = base + j * THREADS + tid;
        x[j] = P[idx * 3 + 0];
        y[j] = P[idx * 3 + 1];
        z[j] = P[idx * 3 + 2];
        dist[j] = 1e10;              // never survives iteration 0
    }

    double qx = (double)P[0], qy = (double)P[1], qz = (double)P[2];
    if (blk == 0 && tid == 0) out[g * NPOINTS] = 0;

    for (int it = 0; it < NPOINTS - 1; ++it) {
        // ---- f64 min-dist update + thread-local argmax (first-max) ----
        double bd = -1.0;
        int    bi = 0x7FFFFFFF;
        float  lx = 0.f, ly = 0.f, lz = 0.f;
        {
#pragma clang fp contract(off)
#pragma unroll
            for (int j = 0; j < PPT; ++j) {
                const double dx = (double)x[j] - qx;
                const double dy = (double)y[j] - qy;
                const double dz = (double)z[j] - qz;
                const double d  = (dx * dx + dy * dy) + dz * dz;
                const double nd = fmin(dist[j], d);
                dist[j] = nd;
                const bool t = nd > bd;          // strict: first-max kept
                bd = t ? nd : bd;
                bi = t ? (base + j * THREADS + tid) : bi;
                lx = t ? x[j] : lx;
                ly = t ? y[j] : ly;
                lz = t ? z[j] : lz;
            }
        }

        // ---- 64-lane butterfly argmax over (bd, bi) ----
#pragma unroll
        for (int m = 1; m < 64; m <<= 1) {
            const double od = __shfl_xor(bd, m, 64);
            const int    oi = __shfl_xor(bi, m, 64);
            const bool t = (od > bd) || (od == bd && oi < bi);
            bd = t ? od : bd; bi = t ? oi : bi;
        }
        // wave-winner lane derivable from idx: tid-part & 63
        const int lwin = bi & 63;
        const float wxf = __shfl(lx, lwin, 64);
        const float wyf = __shfl(ly, lwin, 64);
        const float wzf = __shfl(lz, lwin, 64);

        if (lane == 0) {
            s_bd[wave] = bd; s_bi[wave] = bi;
            s_x[wave] = wxf; s_y[wave] = wyf; s_z[wave] = wzf;
        }
        __syncthreads();

        const unsigned tag = (unsigned)(it + 1);
        const int par = it & 1;
        unsigned long long* rb =
            slots + (size_t)(par * NBATCH + g) * REGION_U64;

        if (tid == 0) {
            // combine the block's 8 wave candidates
            double cd = s_bd[0]; int ci = s_bi[0];
            float cx = s_x[0], cy = s_y[0], cz = s_z[0];
#pragma unroll
            for (int w = 1; w < WAVES; ++w) {
                const double od = s_bd[w]; const int oi = s_bi[w];
                const bool t = (od > cd) || (od == cd && oi < ci);
                cd = t ? od : cd; ci = t ? oi : ci;
                cx = t ? s_x[w] : cx; cy = t ? s_y[w] : cy;
                cz = t ? s_z[w] : cz;
            }
            // publish 4 self-tagged words into this block's own line
            const unsigned long long B =
                (unsigned long long)__double_as_longlong(cd);
            const unsigned X = __float_as_uint(cx);
            const unsigned Y = __float_as_uint(cy);
            const unsigned Z = __float_as_uint(cz);
            const unsigned long long T  = (unsigned long long)tag << 16;
            const unsigned long long I  = (unsigned long long)((unsigned)ci & 0xFFFFu);
            unsigned long long* sp = rb + blk * SLOT_U64;
            __hip_atomic_store(sp + 0, ((B >> 32) << 32)            | T | I,
                               __ATOMIC_RELAXED, __HIP_MEMORY_SCOPE_AGENT);
            __hip_atomic_store(sp + 1, ((B & 0xFFFFFFFFull) << 32)  | T | (X >> 16),
                               __ATOMIC_RELAXED, __HIP_MEMORY_SCOPE_AGENT);
            __hip_atomic_store(sp + 2, ((unsigned long long)Y << 32)| T | (X & 0xFFFFu),
                               __ATOMIC_RELAXED, __HIP_MEMORY_SCOPE_AGENT);
            __hip_atomic_store(sp + 3, ((unsigned long long)Z << 32)| T | I,
                               __ATOMIC_RELAXED, __HIP_MEMORY_SCOPE_AGENT);
        }

        // ---- poll: lane i watches slot (i&7); 8 lines per retry ----
        unsigned long long* sp = rb + (lane & 7) * SLOT_U64;
        unsigned long long l0, l1, l2, l3;
        int guard = 0;
        bool ok;
        do {
            l0 = __hip_atomic_load(sp + 0, __ATOMIC_RELAXED,
                                   __HIP_MEMORY_SCOPE_AGENT);
            l1 = __hip_atomic_load(sp + 1, __ATOMIC_RELAXED,
                                   __HIP_MEMORY_SCOPE_AGENT);
            l2 = __hip_atomic_load(sp + 2, __ATOMIC_RELAXED,
                                   __HIP_MEMORY_SCOPE_AGENT);
            l3 = __hip_atomic_load(sp + 3, __ATOMIC_RELAXED,
                                   __HIP_MEMORY_SCOPE_AGENT);
            ok = (((unsigned)(l0 >> 16) & 0xFFFFu) == tag)
               & (((unsigned)(l1 >> 16) & 0xFFFFu) == tag)
               & (((unsigned)(l2 >> 16) & 0xFFFFu) == tag)
               & (((unsigned)(l3 >> 16) & 0xFFFFu) == tag);
        } while (!ok && ++guard < (1 << 20));   // fail loud, never hang

        double cd = __longlong_as_double(
            (long long)(((l0 >> 32) << 32) | (l1 >> 32)));
        int    ci = (int)(l0 & 0xFFFFull);
        const float cx = __uint_as_float(
            (unsigned)(((l1 & 0xFFFFull) << 16) | (l2 & 0xFFFFull)));
        const float cy = __uint_as_float((unsigned)(l2 >> 32));
        const float cz = __uint_as_float((unsigned)(l3 >> 32));

        // ---- 3-stage butterfly within each 8-lane group (slots 0..7) ----
#pragma unroll
        for (int m = 1; m < 8; m <<= 1) {
            const double od = __shfl_xor(cd, m, 64);
            const int    oi = __shfl_xor(ci, m, 64);
            const bool t = (od > cd) || (od == cd && oi < ci);
            cd = t ? od : cd; ci = t ? oi : ci;
        }
        // winner's slot from its index (8192 pts/block): blk = ci>>13
        const int wslot = ci >> 13;
        const int srcl  = (lane & 56) | wslot;    // same 8-group, winning slot
        const float px = __shfl(cx, srcl, 64);
        const float py = __shfl(cy, srcl, 64);
        const float pz = __shfl(cz, srcl, 64);

        qx = (double)px; qy = (double)py; qz = (double)pz;

        if (blk == 0 && tid == 0) out[g * NPOINTS + it + 1] = ci;
    }
}

extern "C" void kernel_launch(void* const* d_in, const int* in_sizes, int n_in,
                              void* d_out, int out_size, void* d_ws, size_t ws_size,
                              hipStream_t stream) {
    (void)in_sizes; (void)n_in; (void)out_size; (void)ws_size;
    // d_in[0] = npoints (scalar, fixed 2048 per setup), d_in[1] = t_in
    const float* t_in = (const float*)d_in[1];
    int* out = (int*)d_out;
    unsigned long long* slots = (unsigned long long*)d_ws;  // 16 KB used

    dim3 grid(NBATCH * KBLK);
    dim3 block(THREADS);
    void* args[] = { (void*)&t_in, (void*)&out, (void*)&slots };
    hipLaunchCooperativeKernel((const void*)fps_kernel, grid, block, args, 0, stream);
}

// Round 10
// 7055.362 us; speedup vs baseline: 1.6926x; 1.6926x over previous
//
#include <hip/hip_runtime.h>
#include <stdint.h>

// Farthest point sampling: b=16, n=65536, npoints=2048. Full-f64 decision
// pipeline (R5: harness ref is float64 ground-truth recompute; R5-R9 absmax 0).
//
// R10 = R7 (best: 4.52 us/iter) + poller reduction. Cross-round model:
// rendezvous latency = fabric RT + queueing(per-line spin-load rate).
//  R7: 64 waves/batch poll 5 words over 64 lines  -> 4.52 us/iter
//  R8: SoA false sharing (8 writers/line)         -> 5.02 (write contention)
//  R9: all polls on 8 lines + serialized publish  -> 5.83 (read contention)
// So: publish stays per-wave immediate (single-writer 64-B slot, lanes 0..3
// store the 4 self-tagged words -> one coalesced line write), but only
// WAVE 0 of each block polls (16 pollers/batch instead of 64; 4 words not
// 5 -> ~5x less spin traffic). Wave 0 then reduces, derives the winning
// slot from the index, shuffles coords, and broadcasts {idx,x,y,z} to its
// block via LDS + one __syncthreads (intra-CU, ~200 cy; R9's regression was
// the serialized PUBLISH path, not the broadcast).
// Slot words: w0=[bd_hi32|tag|idx] w1=[bd_lo32|tag|x_hi16]
//             w2=[y|tag|x_lo16]    w3=[z|tag|idx]
// Protocol invariants unchanged: parity double-buffer, unique 16-bit tags
// (poison 0xAAAA unmatchable), skew <= 1 iteration via the rendezvous chain
// (overwrite at it+2 happens-after all reads at it: writer passed barrier
// it+1 => its wave0 saw every slot{it+1} => every block passed barrier{it}
// => every wave0 consumed slots{it}).

#define NBATCH   16
#define NPTS     65536
#define NPOINTS  2048
#define KBLK     16                  // blocks per batch
#define THREADS  256
#define WPB      64                  // waves per batch == wave width
#define PPB      4096                // points per block
#define PPT      16                  // points per thread
#define SLOT_U64 8                   // one 64-B line per slot, single writer
#define REGION_U64 (WPB * SLOT_U64)  // 4 KB per (parity,batch)

__global__ __launch_bounds__(THREADS, 1)
void fps_kernel(const float* __restrict__ pts, int* __restrict__ out,
                unsigned long long* __restrict__ slots)
{
    const int bid  = blockIdx.x;
    const int g    = bid & 15;       // batch (XCD co-location swizzle)
    const int blk  = bid >> 4;       // block within batch, 0..15
    const int tid  = threadIdx.x;
    const int lane = tid & 63;
    const int wave = tid >> 6;       // 0..3
    const int widx = (blk << 2) + wave;   // slot index within batch, 0..63

    const float* __restrict__ P = pts + (size_t)g * (NPTS * 3);

    __shared__ unsigned s_res[4];    // {idx, xbits, ybits, zbits}

    // Register-resident coords (f32; exact when widened to f64) + f64 dist.
    float  x[PPT], y[PPT], z[PPT];
    double dist[PPT];
    const int base = blk * PPB;
#pragma unroll
    for (int j = 0; j < PPT; ++j) {
        const int idx = base + j * THREADS + tid;
        x[j] = P[idx * 3 + 0];
        y[j] = P[idx * 3 + 1];
        z[j] = P[idx * 3 + 2];
        dist[j] = 1e10;              // never survives iteration 0
    }

    double qx = (double)P[0], qy = (double)P[1], qz = (double)P[2];
    if (blk == 0 && tid == 0) out[g * NPOINTS] = 0;

    for (int it = 0; it < NPOINTS - 1; ++it) {
        // ---- f64 min-dist update + thread-local argmax (first-max) ----
        double bd = -1.0;
        int    bi = 0x7FFFFFFF;
        float  lx = 0.f, ly = 0.f, lz = 0.f;
        {
#pragma clang fp contract(off)
#pragma unroll
            for (int j = 0; j < PPT; ++j) {
                const double dx = (double)x[j] - qx;
                const double dy = (double)y[j] - qy;
                const double dz = (double)z[j] - qz;
                const double d  = (dx * dx + dy * dy) + dz * dz;
                const double nd = fmin(dist[j], d);
                dist[j] = nd;
                const bool t = nd > bd;          // strict: first-max kept
                bd = t ? nd : bd;
                bi = t ? (base + j * THREADS + tid) : bi;
                lx = t ? x[j] : lx;
                ly = t ? y[j] : ly;
                lz = t ? z[j] : lz;
            }
        }

        // ---- 64-lane butterfly argmax over (bd, bi) ----
#pragma unroll
        for (int m = 1; m < 64; m <<= 1) {
            const double od = __shfl_xor(bd, m, 64);
            const int    oi = __shfl_xor(bi, m, 64);
            const bool t = (od > bd) || (od == bd && oi < bi);
            bd = t ? od : bd; bi = t ? oi : bi;
        }
        // wave-winner lane from idx (tid = bi&255, lane = bi&63)
        const int lwin = bi & 63;
        const float wxf = __shfl(lx, lwin, 64);
        const float wyf = __shfl(ly, lwin, 64);
        const float wzf = __shfl(lz, lwin, 64);

        const unsigned tag = (unsigned)(it + 1);
        const int par = it & 1;
        unsigned long long* rb =
            slots + (size_t)(par * NBATCH + g) * REGION_U64;

        // ---- publish immediately: lanes 0..3 store the 4 self-tagged
        //      words of THIS wave's slot (one coalesced line write) ----
        {
            const unsigned long long B =
                (unsigned long long)__double_as_longlong(bd);
            const unsigned X = __float_as_uint(wxf);
            const unsigned Y = __float_as_uint(wyf);
            const unsigned Z = __float_as_uint(wzf);
            const unsigned long long T = (unsigned long long)tag << 16;
            const unsigned long long I =
                (unsigned long long)((unsigned)bi & 0xFFFFu);

            const unsigned long long hi32 =
                  (lane == 0) ? (B >> 32)
                : (lane == 1) ? (B & 0xFFFFFFFFull)
                : (lane == 2) ? (unsigned long long)Y
                              : (unsigned long long)Z;
            const unsigned long long lo16 =
                  (lane == 0) ? I
                : (lane == 1) ? (unsigned long long)(X >> 16)
                : (lane == 2) ? (unsigned long long)(X & 0xFFFFu)
                              : I;
            if (lane < 4) {
                __hip_atomic_store(rb + widx * SLOT_U64 + lane,
                                   (hi32 << 32) | T | lo16,
                                   __ATOMIC_RELAXED, __HIP_MEMORY_SCOPE_AGENT);
            }
        }

        if (wave == 0) {
            // ---- poll: lane i watches slot i, all 4 words in one spin ----
            unsigned long long* sp = rb + lane * SLOT_U64;
            unsigned long long l0, l1, l2, l3;
            int guard = 0;
            bool ok;
            do {
                l0 = __hip_atomic_load(sp + 0, __ATOMIC_RELAXED,
                                       __HIP_MEMORY_SCOPE_AGENT);
                l1 = __hip_atomic_load(sp + 1, __ATOMIC_RELAXED,
                                       __HIP_MEMORY_SCOPE_AGENT);
                l2 = __hip_atomic_load(sp + 2, __ATOMIC_RELAXED,
                                       __HIP_MEMORY_SCOPE_AGENT);
                l3 = __hip_atomic_load(sp + 3, __ATOMIC_RELAXED,
                                       __HIP_MEMORY_SCOPE_AGENT);
                ok = (((unsigned)(l0 >> 16) & 0xFFFFu) == tag)
                   & (((unsigned)(l1 >> 16) & 0xFFFFu) == tag)
                   & (((unsigned)(l2 >> 16) & 0xFFFFu) == tag)
                   & (((unsigned)(l3 >> 16) & 0xFFFFu) == tag);
            } while (!ok && ++guard < (1 << 20));   // fail loud, never hang

            double cd = __longlong_as_double(
                (long long)(((l0 >> 32) << 32) | (l1 >> 32)));
            int    ci = (int)(l0 & 0xFFFFull);
            const float cx = __uint_as_float(
                (unsigned)(((l1 & 0xFFFFull) << 16) | (l2 & 0xFFFFull)));
            const float cy = __uint_as_float((unsigned)(l2 >> 32));
            const float cz = __uint_as_float((unsigned)(l3 >> 32));

            // ---- 64-lane butterfly over (cd, ci) for the batch winner ----
#pragma unroll
            for (int m = 1; m < 64; m <<= 1) {
                const double od = __shfl_xor(cd, m, 64);
                const int    oi = __shfl_xor(ci, m, 64);
                const bool t = (od > cd) || (od == cd && oi < ci);
                cd = t ? od : cd; ci = t ? oi : ci;
            }
            // winner's owning slot from its index:
            // blk = ci>>12 (4096/block), wave = (ci>>6)&3
            const int ws = ((ci >> 12) << 2) | ((ci >> 6) & 3);
            const float px = __shfl(cx, ws, 64);
            const float py = __shfl(cy, ws, 64);
            const float pz = __shfl(cz, ws, 64);

            if (lane == 0) {
                s_res[0] = (unsigned)ci;
                s_res[1] = __float_as_uint(px);
                s_res[2] = __float_as_uint(py);
                s_res[3] = __float_as_uint(pz);
                if (blk == 0) out[g * NPOINTS + it + 1] = ci;
            }
        }
        __syncthreads();
        qx = (double)__uint_as_float(s_res[1]);
        qy = (double)__uint_as_float(s_res[2]);
        qz = (double)__uint_as_float(s_res[3]);
    }
}

extern "C" void kernel_launch(void* const* d_in, const int* in_sizes, int n_in,
                              void* d_out, int out_size, void* d_ws, size_t ws_size,
                              hipStream_t stream) {
    (void)in_sizes; (void)n_in; (void)out_size; (void)ws_size;
    // d_in[0] = npoints (scalar, fixed 2048 per setup), d_in[1] = t_in
    const float* t_in = (const float*)d_in[1];
    int* out = (int*)d_out;
    unsigned long long* slots = (unsigned long long*)d_ws;  // 128 KB used

    dim3 grid(NBATCH * KBLK);
    dim3 block(THREADS);
    void* args[] = { (void*)&t_in, (void*)&out, (void*)&slots };
    hipLaunchCooperativeKernel((const void*)fps_kernel, grid, block, args, 0, stream);
}

// Round 11
// 5511.443 us; speedup vs baseline: 2.1668x; 1.2801x over previous
//
#include <hip/hip_runtime.h>
#include <stdint.h>

// Farthest point sampling: b=16, n=65536, npoints=2048. Full-f64 decision
// pipeline (R5: harness ref is float64 ground-truth recompute; R5-R10 absmax 0).
//
// R11 = R10 (7.06 ms, prediction matched -> contention model validated) with
// three serial-chain cuts:
//  1. Slots 4->2 self-tagged words (bd 64b + idx 16b only):
//       w0=[bd_hi32|tag|idx]  w1=[bd_lo32|tag|idx]
//     Spin = 2 loads + 2 checks (shorter period, half the per-line queueing).
//     Winner coords now come from a uniform read-only fetch P[wi] done by
//     EVERY wave in parallel after learning wi (L2-resident ~250 cy,
//     overlapped across waves instead of riding the slot).
//  2. __syncthreads -> LDS mailbox: wave0 publishes {idx<<32|tag} as ONE
//     atomic b64 LDS word (workgroup scope, parity-duplexed, zero-init once
//     before the loop; 0 never matches tag>=1). Waves 1-3 spin on it
//     (~60 cy) instead of a full barrier.
//  3. s_sleep(4) before wave0's first poll round: the first round cannot
//     succeed (needs the slowest of 64 publishers) — skip the guaranteed-
//     wasted fabric round that delays the publishers themselves.
// Protocol invariants unchanged: single-writer 64-B slot lines, parity
// double-buffer, unique 16-bit tags (poison 0xAAAA unmatchable), skew <= 1
// iteration via the rendezvous chain (slot overwrite at it+2 happens-after
// all reads at it; LDS mailbox overwrite at it+2 happens-after waves 1-3
// consumed it, since their it+1 publishes gate wave0's it+1 detect).

#define NBATCH   16
#define NPTS     65536
#define NPOINTS  2048
#define KBLK     16                  // blocks per batch
#define THREADS  256
#define WPB      64                  // slots (waves) per batch
#define PPB      4096                // points per block
#define PPT      16                  // points per thread
#define SLOT_U64 8                   // 64-B stride: single writer per line
#define REGION_U64 (WPB * SLOT_U64)  // 4 KB per (parity,batch)

__global__ __launch_bounds__(THREADS, 1)
void fps_kernel(const float* __restrict__ pts, int* __restrict__ out,
                unsigned long long* __restrict__ slots)
{
    const int bid  = blockIdx.x;
    const int g    = bid & 15;       // batch (XCD co-location swizzle)
    const int blk  = bid >> 4;       // block within batch, 0..15
    const int tid  = threadIdx.x;
    const int lane = tid & 63;
    const int wave = tid >> 6;       // 0..3
    const int widx = (blk << 2) + wave;   // slot index within batch, 0..63

    const float* __restrict__ P = pts + (size_t)g * (NPTS * 3);

    __shared__ unsigned long long s_flag[2];   // [idx<<32 | tag], per parity

    // Register-resident coords (f32; exact when widened to f64) + f64 dist.
    float  x[PPT], y[PPT], z[PPT];
    double dist[PPT];
    const int base = blk * PPB;
#pragma unroll
    for (int j = 0; j < PPT; ++j) {
        const int idx = base + j * THREADS + tid;
        x[j] = P[idx * 3 + 0];
        y[j] = P[idx * 3 + 1];
        z[j] = P[idx * 3 + 2];
        dist[j] = 1e10;              // never survives iteration 0
    }
    if (tid == 0) { s_flag[0] = 0ull; s_flag[1] = 0ull; }
    __syncthreads();                 // once, before the loop

    double qx = (double)P[0], qy = (double)P[1], qz = (double)P[2];
    if (blk == 0 && tid == 0) out[g * NPOINTS] = 0;

    for (int it = 0; it < NPOINTS - 1; ++it) {
        // ---- f64 min-dist update + thread-local argmax (first-max) ----
        double bd = -1.0;
        int    bi = 0x7FFFFFFF;
        {
#pragma clang fp contract(off)
#pragma unroll
            for (int j = 0; j < PPT; ++j) {
                const double dx = (double)x[j] - qx;
                const double dy = (double)y[j] - qy;
                const double dz = (double)z[j] - qz;
                const double d  = (dx * dx + dy * dy) + dz * dz;
                const double nd = fmin(dist[j], d);
                dist[j] = nd;
                const bool t = nd > bd;          // strict: first-max kept
                bd = t ? nd : bd;
                bi = t ? (base + j * THREADS + tid) : bi;
            }
        }

        // ---- 64-lane butterfly argmax over (bd, bi) ----
#pragma unroll
        for (int m = 1; m < 64; m <<= 1) {
            const double od = __shfl_xor(bd, m, 64);
            const int    oi = __shfl_xor(bi, m, 64);
            const bool t = (od > bd) || (od == bd && oi < bi);
            bd = t ? od : bd; bi = t ? oi : bi;
        }

        const unsigned tag = (unsigned)(it + 1);
        const int par = it & 1;
        unsigned long long* rb =
            slots + (size_t)(par * NBATCH + g) * REGION_U64;

        // ---- publish: lanes 0..1 store the 2 self-tagged words ----
        {
            const unsigned long long B =
                (unsigned long long)__double_as_longlong(bd);
            const unsigned long long TI =
                  ((unsigned long long)tag << 16)
                | (unsigned long long)((unsigned)bi & 0xFFFFu);
            const unsigned long long hi32 =
                (lane == 0) ? (B >> 32) : (B & 0xFFFFFFFFull);
            if (lane < 2) {
                __hip_atomic_store(rb + widx * SLOT_U64 + lane,
                                   (hi32 << 32) | TI,
                                   __ATOMIC_RELAXED, __HIP_MEMORY_SCOPE_AGENT);
            }
        }

        int wi;
        if (wave == 0) {
            // ---- poll: lane i watches slot i (2 words, one spin loop) ----
            unsigned long long* sp = rb + lane * SLOT_U64;
            __builtin_amdgcn_s_sleep(4);   // first round can't succeed
            unsigned long long l0, l1;
            int guard = 0;
            bool ok;
            do {
                l0 = __hip_atomic_load(sp + 0, __ATOMIC_RELAXED,
                                       __HIP_MEMORY_SCOPE_AGENT);
                l1 = __hip_atomic_load(sp + 1, __ATOMIC_RELAXED,
                                       __HIP_MEMORY_SCOPE_AGENT);
                ok = (((unsigned)(l0 >> 16) & 0xFFFFu) == tag)
                   & (((unsigned)(l1 >> 16) & 0xFFFFu) == tag);
            } while (!ok && ++guard < (1 << 20));   // fail loud, never hang

            double cd = __longlong_as_double(
                (long long)(((l0 >> 32) << 32) | (l1 >> 32)));
            int    ci = (int)(l0 & 0xFFFFull);

            // ---- 64-lane butterfly over (cd, ci) for the batch winner ----
#pragma unroll
            for (int m = 1; m < 64; m <<= 1) {
                const double od = __shfl_xor(cd, m, 64);
                const int    oi = __shfl_xor(ci, m, 64);
                const bool t = (od > cd) || (od == cd && oi < ci);
                cd = t ? od : cd; ci = t ? oi : ci;
            }

            if (lane == 0) {
                // LDS mailbox: one atomic b64 write {idx|tag}
                __hip_atomic_store(&s_flag[par],
                                   ((unsigned long long)(unsigned)ci << 32)
                                 | (unsigned long long)tag,
                                   __ATOMIC_RELAXED,
                                   __HIP_MEMORY_SCOPE_WORKGROUP);
                if (blk == 0) out[g * NPOINTS + it + 1] = ci;
            }
            wi = ci;
        } else {
            // ---- waves 1..3: spin on the LDS mailbox (intra-CU) ----
            unsigned long long fv;
            int guard = 0;
            do {
                fv = __hip_atomic_load(&s_flag[par], __ATOMIC_RELAXED,
                                       __HIP_MEMORY_SCOPE_WORKGROUP);
            } while (((unsigned)fv != tag) && ++guard < (1 << 20));
            wi = (int)(fv >> 32);
        }

        // ---- winner coords: uniform read-only fetch, per wave in parallel
        const float* pw = P + (size_t)(unsigned)wi * 3;
        qx = (double)pw[0]; qy = (double)pw[1]; qz = (double)pw[2];
    }
}

extern "C" void kernel_launch(void* const* d_in, const int* in_sizes, int n_in,
                              void* d_out, int out_size, void* d_ws, size_t ws_size,
                              hipStream_t stream) {
    (void)in_sizes; (void)n_in; (void)out_size; (void)ws_size;
    // d_in[0] = npoints (scalar, fixed 2048 per setup), d_in[1] = t_in
    const float* t_in = (const float*)d_in[1];
    int* out = (int*)d_out;
    unsigned long long* slots = (unsigned long long*)d_ws;  // 128 KB used

    dim3 grid(NBATCH * KBLK);
    dim3 block(THREADS);
    void* args[] = { (void*)&t_in, (void*)&out, (void*)&slots };
    hipLaunchCooperativeKernel((const void*)fps_kernel, grid, block, args, 0, stream);
}